// Round 1
// baseline (543.443 us; speedup 1.0000x reference)
//
#include <hip/hip_runtime.h>

#define B_DIM 32
#define C_DIM 64
#define D_DIM 64
#define T_DIM 30000
#define T2    15000   // T in float2 units
#define T4    7500    // T in float4 units

// ---------------- Kernel A: desc[b,c] = mean over T ----------------
__global__ __launch_bounds__(256) void mean_kernel(const float* __restrict__ x,
                                                   float* __restrict__ desc) {
    int r = blockIdx.x;  // b*64 + c
    const float4* xr = (const float4*)(x + (size_t)r * T_DIM);
    float4 s = {0.f, 0.f, 0.f, 0.f};
    for (int i = threadIdx.x; i < T4; i += 256) {
        float4 v = xr[i];
        s.x += v.x; s.y += v.y; s.z += v.z; s.w += v.w;
    }
    float p = (s.x + s.y) + (s.z + s.w);
    #pragma unroll
    for (int off = 32; off > 0; off >>= 1) p += __shfl_down(p, off, 64);
    __shared__ float wsum[4];
    int wave = threadIdx.x >> 6;
    int lane = threadIdx.x & 63;
    if (lane == 0) wsum[wave] = p;
    __syncthreads();
    if (threadIdx.x == 0) {
        float tot = (wsum[0] + wsum[1]) + (wsum[2] + wsum[3]);
        desc[r] = tot * (1.0f / (float)T_DIM);
    }
}

// ---------------- Kernel B: attn[b,c,e] = softmax_e(logits) ----------------
// logits = (A*dc*de + Bq*dc + Bk*de + Cc) / sqrt(D)
__global__ __launch_bounds__(64) void attn_kernel(const float* __restrict__ desc,
                                                  const float* __restrict__ Wq,
                                                  const float* __restrict__ bq,
                                                  const float* __restrict__ Wk,
                                                  const float* __restrict__ bk,
                                                  float* __restrict__ attn) {
    int b = blockIdx.x;
    int c = threadIdx.x;
    __shared__ float sd[C_DIM];
    sd[c] = desc[b * C_DIM + c];
    __syncthreads();

    float dA = 0.f, dBq = 0.f, dBk = 0.f, dCc = 0.f;
    #pragma unroll
    for (int d = 0; d < D_DIM; ++d) {
        float wq = Wq[d], wk = Wk[d], vq = bq[d], vk = bk[d];
        dA  += wq * wk;
        dBq += wq * vk;
        dBk += vq * wk;
        dCc += vq * vk;
    }

    float dc = sd[c];
    float l[C_DIM];
    float lmax = -1e30f;
    #pragma unroll
    for (int e = 0; e < C_DIM; ++e) {
        float de = sd[e];
        float v = (dA * dc * de + dBq * dc + dBk * de + dCc) * 0.125f;
        l[e] = v;
        lmax = fmaxf(lmax, v);
    }
    float sum = 0.f;
    #pragma unroll
    for (int e = 0; e < C_DIM; ++e) {
        float ev = __expf(l[e] - lmax);
        l[e] = ev;
        sum += ev;
    }
    float inv = 1.0f / sum;
    float* arow = attn + ((size_t)b * C_DIM + c) * C_DIM;
    #pragma unroll
    for (int e = 0; e < C_DIM; ++e) arow[e] = l[e] * inv;
}

// ---------------- Kernel C: out = x + alpha * (attn @ x) ----------------
// block = (t-tile of 512 floats, b); each thread owns 2 t-columns (float2)
__global__ __launch_bounds__(256) void mix_kernel(const float* __restrict__ x,
                                                  const float* __restrict__ attn,
                                                  const float* __restrict__ alphap,
                                                  float* __restrict__ out) {
    int b = blockIdx.y;
    __shared__ float4 sA[C_DIM * 16];  // attn[b] as float4 rows: [c][e4]
    const float4* ag = (const float4*)(attn + (size_t)b * C_DIM * C_DIM);
    for (int i = threadIdx.x; i < C_DIM * 16; i += 256) sA[i] = ag[i];
    __syncthreads();

    int j = blockIdx.x * 256 + threadIdx.x;  // float2 column index
    if (j >= T2) return;

    float alpha = alphap[0];
    const float2* xb = (const float2*)x + (size_t)b * C_DIM * T2;
    float2 xcol[C_DIM];
    #pragma unroll
    for (int e = 0; e < C_DIM; ++e) xcol[e] = xb[(size_t)e * T2 + j];

    float2* ob = (float2*)out + (size_t)b * C_DIM * T2;

    #pragma unroll 2
    for (int c = 0; c < C_DIM; ++c) {
        float ax0 = 0.f, ay0 = 0.f, ax1 = 0.f, ay1 = 0.f;
        float ax2 = 0.f, ay2 = 0.f, ax3 = 0.f, ay3 = 0.f;
        #pragma unroll
        for (int e4 = 0; e4 < 16; ++e4) {
            float4 a4 = sA[c * 16 + e4];
            float2 x0 = xcol[e4 * 4 + 0];
            float2 x1 = xcol[e4 * 4 + 1];
            float2 x2 = xcol[e4 * 4 + 2];
            float2 x3 = xcol[e4 * 4 + 3];
            ax0 += a4.x * x0.x; ay0 += a4.x * x0.y;
            ax1 += a4.y * x1.x; ay1 += a4.y * x1.y;
            ax2 += a4.z * x2.x; ay2 += a4.z * x2.y;
            ax3 += a4.w * x3.x; ay3 += a4.w * x3.y;
        }
        float accx = (ax0 + ax1) + (ax2 + ax3);
        float accy = (ay0 + ay1) + (ay2 + ay3);
        float2 r;
        r.x = xcol[c].x + alpha * accx;
        r.y = xcol[c].y + alpha * accy;
        ob[(size_t)c * T2 + j] = r;
    }
}

extern "C" void kernel_launch(void* const* d_in, const int* in_sizes, int n_in,
                              void* d_out, int out_size, void* d_ws, size_t ws_size,
                              hipStream_t stream) {
    const float* x     = (const float*)d_in[0];
    const float* Wq    = (const float*)d_in[1];
    const float* bq    = (const float*)d_in[2];
    const float* Wk    = (const float*)d_in[3];
    const float* bk    = (const float*)d_in[4];
    // d_in[5] = Wv, d_in[6] = bv: dead code in the reference
    const float* alpha = (const float*)d_in[7];
    float* out = (float*)d_out;

    float* desc = (float*)d_ws;                    // B*C floats
    float* attn = desc + B_DIM * C_DIM;            // B*C*C floats

    mean_kernel<<<B_DIM * C_DIM, 256, 0, stream>>>(x, desc);
    attn_kernel<<<B_DIM, 64, 0, stream>>>(desc, Wq, bq, Wk, bk, attn);
    dim3 gridC((T2 + 255) / 256, B_DIM);
    mix_kernel<<<gridC, 256, 0, stream>>>(x, attn, alpha, out);
}

// Round 3
// 180.829 us; speedup vs baseline: 3.0053x; 3.0053x over previous
//
#include <hip/hip_runtime.h>

#define B_DIM 32
#define C_DIM 64
#define D_DIM 64
#define T_DIM 30000
#define T4    7500               // T in float4 units
#define TILES 118                // ceil(T4 / 64)
#define NWG   (TILES * B_DIM)    // 3776, divisible by 8

typedef float f32x4 __attribute__((ext_vector_type(4)));

// ---------------- Kernel A: desc[b,c] = mean over T ----------------
__global__ __launch_bounds__(256) void mean_kernel(const float* __restrict__ x,
                                                   float* __restrict__ desc) {
    int r = blockIdx.x;  // b*64 + c
    const float4* xr = (const float4*)(x + (size_t)r * T_DIM);
    float4 s = {0.f, 0.f, 0.f, 0.f};
    for (int i = threadIdx.x; i < T4; i += 256) {
        float4 v = xr[i];
        s.x += v.x; s.y += v.y; s.z += v.z; s.w += v.w;
    }
    float p = (s.x + s.y) + (s.z + s.w);
    #pragma unroll
    for (int off = 32; off > 0; off >>= 1) p += __shfl_down(p, off, 64);
    __shared__ float wsum[4];
    int wave = threadIdx.x >> 6;
    int lane = threadIdx.x & 63;
    if (lane == 0) wsum[wave] = p;
    __syncthreads();
    if (threadIdx.x == 0) {
        float tot = (wsum[0] + wsum[1]) + (wsum[2] + wsum[3]);
        desc[r] = tot * (1.0f / (float)T_DIM);
    }
}

// ---------------- Kernel B: attn2 = alpha * softmax(logits) + I ----------------
// logits = (A*dc*de + Bq*dc + Bk*de + Cc) / sqrt(D)
__global__ __launch_bounds__(64) void attn_kernel(const float* __restrict__ desc,
                                                  const float* __restrict__ Wq,
                                                  const float* __restrict__ bq,
                                                  const float* __restrict__ Wk,
                                                  const float* __restrict__ bk,
                                                  const float* __restrict__ alphap,
                                                  float* __restrict__ attn) {
    int b = blockIdx.x;
    int c = threadIdx.x;
    __shared__ float sd[C_DIM];
    sd[c] = desc[b * C_DIM + c];
    __syncthreads();

    float dA = 0.f, dBq = 0.f, dBk = 0.f, dCc = 0.f;
    #pragma unroll
    for (int d = 0; d < D_DIM; ++d) {
        float wq = Wq[d], wk = Wk[d], vq = bq[d], vk = bk[d];
        dA  += wq * wk;
        dBq += wq * vk;
        dBk += vq * wk;
        dCc += vq * vk;
    }

    float dc = sd[c];
    float l[C_DIM];
    float lmax = -1e30f;
    #pragma unroll
    for (int e = 0; e < C_DIM; ++e) {
        float de = sd[e];
        float v = (dA * dc * de + dBq * dc + dBk * de + dCc) * 0.125f;
        l[e] = v;
        lmax = fmaxf(lmax, v);
    }
    float sum = 0.f;
    #pragma unroll
    for (int e = 0; e < C_DIM; ++e) {
        float ev = __expf(l[e] - lmax);
        l[e] = ev;
        sum += ev;
    }
    float inv = alphap[0] / sum;   // fold alpha into attn
    float* arow = attn + ((size_t)b * C_DIM + c) * C_DIM;
    #pragma unroll
    for (int e = 0; e < C_DIM; ++e)
        arow[e] = l[e] * inv + (e == c ? 1.0f : 0.0f);  // fold residual (identity)
}

// ---------------- Kernel C: out = attn2 @ x  (batched 64x64 @ 64xT) ----------------
// Block = 256 threads (4 waves). Wave w owns c in [16w, 16w+16); lane owns one
// float4 column. attn2 rows are wave-uniform -> scalar loads (SGPR). acc[16]
// float4 = 64 VGPR; launch_bounds(256,4) caps at 128 VGPR -> 16 waves/CU.
__global__ __launch_bounds__(256, 4) void mix_kernel(const float* __restrict__ x,
                                                     const float* __restrict__ attn,
                                                     float* __restrict__ out) {
    // bijective XCD-chunked swizzle (NWG % 8 == 0): each XCD gets a contiguous
    // range of (b, tile) so j-adjacent blocks share an L2 (write-merge at
    // 128B-line tile boundaries + better locality).
    int flat = blockIdx.x;
    int swz  = (flat & 7) * (NWG >> 3) + (flat >> 3);
    int tile = swz % TILES;
    int b    = swz / TILES;

    int lane = threadIdx.x & 63;
    int wv   = __builtin_amdgcn_readfirstlane((int)(threadIdx.x >> 6));
    int c0   = wv << 4;

    int j4   = tile * 64 + lane;          // float4 column index
    bool act = (j4 < T4);
    int j4c  = act ? j4 : (T4 - 1);       // clamp so all lanes load valid addrs

    const float4* xb  = (const float4*)x + (size_t)b * C_DIM * T4;
    const float4* a4p = (const float4*)(attn + ((size_t)b * C_DIM + c0) * C_DIM);

    float4 acc[16];
    #pragma unroll
    for (int i = 0; i < 16; ++i) acc[i] = make_float4(0.f, 0.f, 0.f, 0.f);

    #pragma unroll 4
    for (int e4 = 0; e4 < 16; ++e4) {
        float4 xv0 = xb[(size_t)(e4 * 4 + 0) * T4 + j4c];
        float4 xv1 = xb[(size_t)(e4 * 4 + 1) * T4 + j4c];
        float4 xv2 = xb[(size_t)(e4 * 4 + 2) * T4 + j4c];
        float4 xv3 = xb[(size_t)(e4 * 4 + 3) * T4 + j4c];
        #pragma unroll
        for (int i = 0; i < 16; ++i) {
            float4 a4 = a4p[i * 16 + e4];   // wave-uniform -> s_load_dwordx4
            float4& ai = acc[i];
            ai.x += a4.x * xv0.x; ai.y += a4.x * xv0.y; ai.z += a4.x * xv0.z; ai.w += a4.x * xv0.w;
            ai.x += a4.y * xv1.x; ai.y += a4.y * xv1.y; ai.z += a4.y * xv1.z; ai.w += a4.y * xv1.w;
            ai.x += a4.z * xv2.x; ai.y += a4.z * xv2.y; ai.z += a4.z * xv2.z; ai.w += a4.z * xv2.w;
            ai.x += a4.w * xv3.x; ai.y += a4.w * xv3.y; ai.z += a4.w * xv3.z; ai.w += a4.w * xv3.w;
        }
    }

    if (act) {
        float4* ob = (float4*)out + (size_t)b * C_DIM * T4;
        #pragma unroll
        for (int i = 0; i < 16; ++i) {
            f32x4 v = { acc[i].x, acc[i].y, acc[i].z, acc[i].w };
            __builtin_nontemporal_store(v, (f32x4*)&ob[(size_t)(c0 + i) * T4 + j4]);
        }
    }
}

extern "C" void kernel_launch(void* const* d_in, const int* in_sizes, int n_in,
                              void* d_out, int out_size, void* d_ws, size_t ws_size,
                              hipStream_t stream) {
    const float* x     = (const float*)d_in[0];
    const float* Wq    = (const float*)d_in[1];
    const float* bq    = (const float*)d_in[2];
    const float* Wk    = (const float*)d_in[3];
    const float* bk    = (const float*)d_in[4];
    // d_in[5] = Wv, d_in[6] = bv: dead code in the reference
    const float* alpha = (const float*)d_in[7];
    float* out = (float*)d_out;

    float* desc = (float*)d_ws;                    // B*C floats
    float* attn = desc + B_DIM * C_DIM;            // B*C*C floats

    mean_kernel<<<B_DIM * C_DIM, 256, 0, stream>>>(x, desc);
    attn_kernel<<<B_DIM, 64, 0, stream>>>(desc, Wq, bq, Wk, bk, alpha, attn);
    mix_kernel<<<NWG, 256, 0, stream>>>(x, attn, out);
}

// Round 4
// 172.418 us; speedup vs baseline: 3.1519x; 1.0488x over previous
//
#include <hip/hip_runtime.h>

#define B_DIM 32
#define C_DIM 64
#define D_DIM 64
#define T_DIM 30000
#define T4    7500
#define JTILE 128                 // floats of j per block (4 waves x 32)
#define TILES 235                 // ceil(30000 / 128)
#define NWG   (TILES * B_DIM)     // 7520, divisible by 8

typedef short bf16x8 __attribute__((ext_vector_type(8)));
typedef float f32x16 __attribute__((ext_vector_type(16)));

__device__ __forceinline__ unsigned short f32_to_bf16_rne(float f) {
    unsigned int u = __builtin_bit_cast(unsigned int, f);
    return (unsigned short)((u + 0x7fffu + ((u >> 16) & 1u)) >> 16);
}

// ---------------- Kernel A: desc[b,c] = mean over T ----------------
__global__ __launch_bounds__(256) void mean_kernel(const float* __restrict__ x,
                                                   float* __restrict__ desc) {
    int r = blockIdx.x;  // b*64 + c
    const float4* xr = (const float4*)(x + (size_t)r * T_DIM);
    float4 s = {0.f, 0.f, 0.f, 0.f};
    for (int i = threadIdx.x; i < T4; i += 256) {
        float4 v = xr[i];
        s.x += v.x; s.y += v.y; s.z += v.z; s.w += v.w;
    }
    float p = (s.x + s.y) + (s.z + s.w);
    #pragma unroll
    for (int off = 32; off > 0; off >>= 1) p += __shfl_down(p, off, 64);
    __shared__ float wsum[4];
    int wave = threadIdx.x >> 6;
    int lane = threadIdx.x & 63;
    if (lane == 0) wsum[wave] = p;
    __syncthreads();
    if (threadIdx.x == 0) {
        float tot = (wsum[0] + wsum[1]) + (wsum[2] + wsum[3]);
        desc[r] = tot * (1.0f / (float)T_DIM);
    }
}

// ---------------- Kernel B: attn2 = bf16(alpha * softmax(logits) + I) ----------------
__global__ __launch_bounds__(64) void attn_kernel(const float* __restrict__ desc,
                                                  const float* __restrict__ Wq,
                                                  const float* __restrict__ bq,
                                                  const float* __restrict__ Wk,
                                                  const float* __restrict__ bk,
                                                  const float* __restrict__ alphap,
                                                  unsigned short* __restrict__ attnb) {
    int b = blockIdx.x;
    int c = threadIdx.x;
    __shared__ float sd[C_DIM];
    sd[c] = desc[b * C_DIM + c];
    __syncthreads();

    float dA = 0.f, dBq = 0.f, dBk = 0.f, dCc = 0.f;
    #pragma unroll
    for (int d = 0; d < D_DIM; ++d) {
        float wq = Wq[d], wk = Wk[d], vq = bq[d], vk = bk[d];
        dA  += wq * wk;
        dBq += wq * vk;
        dBk += vq * wk;
        dCc += vq * vk;
    }

    float dc = sd[c];
    float l[C_DIM];
    float lmax = -1e30f;
    #pragma unroll
    for (int e = 0; e < C_DIM; ++e) {
        float de = sd[e];
        float v = (dA * dc * de + dBq * dc + dBk * de + dCc) * 0.125f;
        l[e] = v;
        lmax = fmaxf(lmax, v);
    }
    float sum = 0.f;
    #pragma unroll
    for (int e = 0; e < C_DIM; ++e) {
        float ev = __expf(l[e] - lmax);
        l[e] = ev;
        sum += ev;
    }
    float inv = alphap[0] / sum;   // fold alpha
    unsigned short* arow = attnb + ((size_t)b * C_DIM + c) * C_DIM;
    #pragma unroll
    for (int e = 0; e < C_DIM; ++e) {
        float v = l[e] * inv + (e == c ? 1.0f : 0.0f);  // fold residual
        arow[e] = f32_to_bf16_rne(v);
    }
}

// ---------------- Kernel C: out = attn2 @ x via bf16 MFMA ----------------
// Block = 4 waves; wave w owns j in [tile*128 + 32w, +32). Each wave computes
// all 64 c: 2 M-tiles (32x32) x 4 K-steps (16) = 8 mfma_f32_32x32x16_bf16.
// A-frag: lane holds attn2[32m + (l&31)][16g + 8*(l>>5) + i], i=0..7 (16B global load).
// B-frag: lane holds x[16g + 8*(l>>5) + i][j0 + (l&31)] gathered + cvt to bf16.
// D: col = lane&31 (j), row = (r&3) + 8*(r>>2) + 4*(l>>5).
__global__ __launch_bounds__(256) void mix_mfma(const float* __restrict__ x,
                                                const unsigned short* __restrict__ attnb,
                                                float* __restrict__ out) {
    // chunked XCD swizzle: each XCD gets a contiguous run of (b, tile)
    int flat = blockIdx.x;
    int swz  = (flat & 7) * (NWG / 8) + (flat >> 3);
    int b    = swz / TILES;
    int tile = swz % TILES;

    int w    = threadIdx.x >> 6;
    int l    = threadIdx.x & 63;
    int l31  = l & 31;
    int lhi  = l >> 5;            // 0 or 1

    int j0   = tile * JTILE + w * 32 + l31;   // this lane's j column
    bool jv  = (j0 < T_DIM);
    int jc   = jv ? j0 : (T_DIM - 1);

    // ---- A fragments (attn2, bf16) ----
    const unsigned short* ab = attnb + (size_t)b * C_DIM * C_DIM;
    bf16x8 afrag[2][4];
    #pragma unroll
    for (int m = 0; m < 2; ++m)
        #pragma unroll
        for (int g = 0; g < 4; ++g)
            afrag[m][g] = *(const bf16x8*)(ab + (32 * m + l31) * C_DIM + 16 * g + 8 * lhi);

    // ---- K loop: gather x column, cvt to bf16, MFMA ----
    const float* xb = x + (size_t)b * C_DIM * T_DIM;
    f32x16 acc0 = {}, acc1 = {};

    #pragma unroll
    for (int g = 0; g < 4; ++g) {
        int e0 = 16 * g + 8 * lhi;
        float xv[8];
        #pragma unroll
        for (int i = 0; i < 8; ++i)
            xv[i] = xb[(size_t)(e0 + i) * T_DIM + jc];
        bf16x8 bfrag;
        #pragma unroll
        for (int i = 0; i < 8; ++i)
            bfrag[i] = (short)f32_to_bf16_rne(xv[i]);
        acc0 = __builtin_amdgcn_mfma_f32_32x32x16_bf16(afrag[0][g], bfrag, acc0, 0, 0, 0);
        acc1 = __builtin_amdgcn_mfma_f32_32x32x16_bf16(afrag[1][g], bfrag, acc1, 0, 0, 0);
    }

    // ---- store: row = (r&3) + 8*(r>>2) + 4*lhi, col = j0 ----
    if (jv) {
        float* ob = out + (size_t)b * C_DIM * T_DIM;
        #pragma unroll
        for (int r = 0; r < 16; ++r) {
            int crow = (r & 3) + 8 * (r >> 2) + 4 * lhi;
            ob[(size_t)crow * T_DIM + j0] = acc0[r];
            ob[(size_t)(crow + 32) * T_DIM + j0] = acc1[r];
        }
    }
}

extern "C" void kernel_launch(void* const* d_in, const int* in_sizes, int n_in,
                              void* d_out, int out_size, void* d_ws, size_t ws_size,
                              hipStream_t stream) {
    const float* x     = (const float*)d_in[0];
    const float* Wq    = (const float*)d_in[1];
    const float* bq    = (const float*)d_in[2];
    const float* Wk    = (const float*)d_in[3];
    const float* bk    = (const float*)d_in[4];
    // d_in[5] = Wv, d_in[6] = bv: dead code in the reference
    const float* alpha = (const float*)d_in[7];
    float* out = (float*)d_out;

    float* desc = (float*)d_ws;                              // B*C floats (8 KB)
    unsigned short* attnb = (unsigned short*)(desc + B_DIM * C_DIM);  // B*C*C bf16 (256 KB)

    mean_kernel<<<B_DIM * C_DIM, 256, 0, stream>>>(x, desc);
    attn_kernel<<<B_DIM, 64, 0, stream>>>(desc, Wq, bq, Wk, bk, alpha, attnb);
    mix_mfma<<<NWG, 256, 0, stream>>>(x, attnb, out);
}

// Round 5
// 118.087 us; speedup vs baseline: 4.6021x; 1.4601x over previous
//
#include <hip/hip_runtime.h>

#define B_DIM 32
#define C_DIM 64
#define D_DIM 64
#define T_DIM 30000
#define T4    7500
#define JTILE 128                 // floats of j per block (4 waves x 32)
#define TILES 235                 // ceil(30000 / 128)
#define NWG   (TILES * B_DIM)     // 7520, divisible by 8

typedef short bf16x8 __attribute__((ext_vector_type(8)));
typedef float f32x16 __attribute__((ext_vector_type(16)));
typedef float f32x4  __attribute__((ext_vector_type(4)));

__device__ __forceinline__ unsigned short f32_to_bf16_rne(float f) {
    unsigned int u = __builtin_bit_cast(unsigned int, f);
    return (unsigned short)((u + 0x7fffu + ((u >> 16) & 1u)) >> 16);
}

// ---------------- Kernel A: desc[b,c] = mean over T ----------------
__global__ __launch_bounds__(256) void mean_kernel(const float* __restrict__ x,
                                                   float* __restrict__ desc) {
    int r = blockIdx.x;  // b*64 + c
    const float4* xr = (const float4*)(x + (size_t)r * T_DIM);
    float4 s = {0.f, 0.f, 0.f, 0.f};
    for (int i = threadIdx.x; i < T4; i += 256) {
        float4 v = xr[i];
        s.x += v.x; s.y += v.y; s.z += v.z; s.w += v.w;
    }
    float p = (s.x + s.y) + (s.z + s.w);
    #pragma unroll
    for (int off = 32; off > 0; off >>= 1) p += __shfl_down(p, off, 64);
    __shared__ float wsum[4];
    int wave = threadIdx.x >> 6;
    int lane = threadIdx.x & 63;
    if (lane == 0) wsum[wave] = p;
    __syncthreads();
    if (threadIdx.x == 0) {
        float tot = (wsum[0] + wsum[1]) + (wsum[2] + wsum[3]);
        desc[r] = tot * (1.0f / (float)T_DIM);
    }
}

// ---------------- Kernel B: attn2 = bf16(alpha * softmax(logits) + I) ----------------
__global__ __launch_bounds__(64) void attn_kernel(const float* __restrict__ desc,
                                                  const float* __restrict__ Wq,
                                                  const float* __restrict__ bq,
                                                  const float* __restrict__ Wk,
                                                  const float* __restrict__ bk,
                                                  const float* __restrict__ alphap,
                                                  unsigned short* __restrict__ attnb) {
    int b = blockIdx.x;
    int c = threadIdx.x;
    __shared__ float sd[C_DIM];
    sd[c] = desc[b * C_DIM + c];
    __syncthreads();

    float dA = 0.f, dBq = 0.f, dBk = 0.f, dCc = 0.f;
    #pragma unroll
    for (int d = 0; d < D_DIM; ++d) {
        float wq = Wq[d], wk = Wk[d], vq = bq[d], vk = bk[d];
        dA  += wq * wk;
        dBq += wq * vk;
        dBk += vq * wk;
        dCc += vq * vk;
    }

    float dc = sd[c];
    float l[C_DIM];
    float lmax = -1e30f;
    #pragma unroll
    for (int e = 0; e < C_DIM; ++e) {
        float de = sd[e];
        float v = (dA * dc * de + dBq * dc + dBk * de + dCc) * 0.125f;
        l[e] = v;
        lmax = fmaxf(lmax, v);
    }
    float sum = 0.f;
    #pragma unroll
    for (int e = 0; e < C_DIM; ++e) {
        float ev = __expf(l[e] - lmax);
        l[e] = ev;
        sum += ev;
    }
    float inv = alphap[0] / sum;   // fold alpha
    unsigned short* arow = attnb + ((size_t)b * C_DIM + c) * C_DIM;
    #pragma unroll
    for (int e = 0; e < C_DIM; ++e) {
        float v = l[e] * inv + (e == c ? 1.0f : 0.0f);  // fold residual
        arow[e] = f32_to_bf16_rne(v);
    }
}

// ---------------- Kernel C: out = attn2 @ x via bf16 MFMA, LDS-staged ----------------
// Block = 4 waves, JTILE=128 j-cols. LDS x-tile f32 [64][128] (32 KB), reused
// for the output tile. All LDS access patterns have bank == (l&31): conflict-free.
__global__ __launch_bounds__(256) void mix_mfma(const float* __restrict__ x,
                                                const unsigned short* __restrict__ attnb,
                                                float* __restrict__ out) {
    __shared__ float lx[C_DIM][JTILE];   // 32 KB; x-tile, then out-tile

    // chunked XCD swizzle: same-b adjacent tiles stay on one XCD's L2
    int flat = blockIdx.x;
    int swz  = (flat & 7) * (NWG / 8) + (flat >> 3);
    int b    = swz / TILES;
    int tile = swz % TILES;

    int t   = threadIdx.x;
    int w   = t >> 6;
    int l31 = t & 31;
    int lhi = (t >> 5) & 1;

    // ---- A fragments (attn2, bf16) — issue first, fly under the staging barrier
    const unsigned short* ab = attnb + (size_t)b * C_DIM * C_DIM;
    bf16x8 afrag[2][4];
    #pragma unroll
    for (int m = 0; m < 2; ++m)
        #pragma unroll
        for (int g = 0; g < 4; ++g)
            afrag[m][g] = *(const bf16x8*)(ab + (32 * m + l31) * C_DIM + 16 * g + 8 * lhi);

    // ---- stage x tile: 8 coalesced float4 loads -> ds_write_b128
    const float* xb = x + (size_t)b * C_DIM * T_DIM;
    int cf4  = t & 31;                 // float4 col within tile
    int jf4  = tile * 32 + cf4;        // global float4 col
    int jf4c = (jf4 < T4) ? jf4 : (T4 - 1);
    #pragma unroll
    for (int p = 0; p < 8; ++p) {
        int e = p * 8 + (t >> 5);
        f32x4 v = *(const f32x4*)(xb + (size_t)e * T_DIM + (size_t)jf4c * 4);
        *(f32x4*)&lx[e][cf4 * 4] = v;
    }
    __syncthreads();

    // ---- compute: B-frags from LDS (conflict-free ds_read_b32), cvt, MFMA
    int jc = w * 32 + l31;             // this lane's j col within tile
    f32x16 acc0 = {}, acc1 = {};
    #pragma unroll
    for (int g = 0; g < 4; ++g) {
        int e0 = 16 * g + 8 * lhi;
        bf16x8 bfrag;
        #pragma unroll
        for (int i = 0; i < 8; ++i)
            bfrag[i] = (short)f32_to_bf16_rne(lx[e0 + i][jc]);
        acc0 = __builtin_amdgcn_mfma_f32_32x32x16_bf16(afrag[0][g], bfrag, acc0, 0, 0, 0);
        acc1 = __builtin_amdgcn_mfma_f32_32x32x16_bf16(afrag[1][g], bfrag, acc1, 0, 0, 0);
    }
    __syncthreads();

    // ---- write acc to LDS out-tile (bank = l31, conflict-free)
    #pragma unroll
    for (int r = 0; r < 16; ++r) {
        int crow = (r & 3) + 8 * (r >> 2) + 4 * lhi;
        lx[crow][jc]      = acc0[r];
        lx[crow + 32][jc] = acc1[r];
    }
    __syncthreads();

    // ---- cooperative store-out: ds_read_b128 -> nontemporal dwordx4
    if (jf4 < T4) {
        float* ob = out + (size_t)b * C_DIM * T_DIM;
        #pragma unroll
        for (int p = 0; p < 8; ++p) {
            int e = p * 8 + (t >> 5);
            f32x4 v = *(const f32x4*)&lx[e][cf4 * 4];
            __builtin_nontemporal_store(v, (f32x4*)(ob + (size_t)e * T_DIM + (size_t)jf4 * 4));
        }
    }
}

extern "C" void kernel_launch(void* const* d_in, const int* in_sizes, int n_in,
                              void* d_out, int out_size, void* d_ws, size_t ws_size,
                              hipStream_t stream) {
    const float* x     = (const float*)d_in[0];
    const float* Wq    = (const float*)d_in[1];
    const float* bq    = (const float*)d_in[2];
    const float* Wk    = (const float*)d_in[3];
    const float* bk    = (const float*)d_in[4];
    // d_in[5] = Wv, d_in[6] = bv: dead code in the reference
    const float* alpha = (const float*)d_in[7];
    float* out = (float*)d_out;

    float* desc = (float*)d_ws;                              // B*C floats (8 KB)
    unsigned short* attnb = (unsigned short*)(desc + B_DIM * C_DIM);  // B*C*C bf16 (256 KB)

    mean_kernel<<<B_DIM * C_DIM, 256, 0, stream>>>(x, desc);
    attn_kernel<<<B_DIM, 64, 0, stream>>>(desc, Wq, bq, Wk, bk, alpha, attnb);
    mix_mfma<<<NWG, 256, 0, stream>>>(x, attnb, out);
}